// Round 3
// baseline (106.697 us; speedup 1.0000x reference)
//
#include <hip/hip_runtime.h>

typedef float v2f __attribute__((ext_vector_type(2)));

#define G      8      // images per block (4 packed pairs)
#define NPAIR  4
#define NCLS   10
#define FEATN  3920

__global__ __launch_bounds__(256, 3)
void quanv_fused(const float* __restrict__ x,      // (B, 784)
                 const float* __restrict__ fc_w,   // (10, 3920)
                 const float* __restrict__ fc_b,   // (10,)
                 float* __restrict__ out)          // (B, 10)
{
    const int tid  = threadIdx.x;
    const int img0 = blockIdx.x * G;
    const bool active = tid < 196;
    const int t  = active ? tid : 0;          // clamp: keeps addresses in-bounds
    const int pi = t / 14;
    const int pj = t - pi * 14;
    const int offT = (2 * pi) * 28 + 2 * pj;
    const int offB = offT + 28;
    const float* base = x + (size_t)img0 * 784;

    // Rank-1 feature factors per image pair:
    //   filter feat[m*4+j] = P2[m] * t23[j];  sampler feat[k] = se[k]
    v2f P2[NPAIR][4], t23[NPAIR][4], se[NPAIR][4];

    #pragma unroll
    for (int p = 0; p < NPAIR; ++p) {
        const float* iA = base + (size_t)(2 * p) * 784;
        const float* iB = base + (size_t)(2 * p + 1) * 784;
        const float2 tA = *reinterpret_cast<const float2*>(iA + offT);
        const float2 bA = *reinterpret_cast<const float2*>(iA + offB);
        const float2 tB = *reinterpret_cast<const float2*>(iB + offT);
        const float2 bB = *reinterpret_cast<const float2*>(iB + offB);

        float sA0,cA0,sA1,cA1,sA2,cA2,sA3,cA3;
        float sB0,cB0,sB1,cB1,sB2,cB2,sB3,cB3;
        __sincosf(0.5f * tA.x, &sA0, &cA0); __sincosf(0.5f * tA.y, &sA1, &cA1);
        __sincosf(0.5f * bA.x, &sA2, &cA2); __sincosf(0.5f * bA.y, &sA3, &cA3);
        __sincosf(0.5f * tB.x, &sB0, &cB0); __sincosf(0.5f * tB.y, &sB1, &cB1);
        __sincosf(0.5f * bB.x, &sB2, &cB2); __sincosf(0.5f * bB.y, &sB3, &cB3);

        const v2f c0 = {cA0, cB0}, s0 = {sA0, sB0};
        const v2f c1 = {cA1, cB1}, s1 = {sA1, sB1};

        v2f a00 = c0 * c1, a01 = c0 * s1, a10 = s0 * c1, a11 = s0 * s1;
        #pragma unroll
        for (int r = 0; r < 8; ++r) {
            const v2f b10 = a11, b11 = a10;           // CX(0,1)
            const v2f n00 = c0 * a00 - s0 * b10;      // RY(p0) on q0
            const v2f n01 = c0 * a01 - s0 * b11;
            const v2f n10 = s0 * a00 + c0 * b10;
            const v2f n11 = s0 * a01 + c0 * b11;
            a00 = n00; a01 = n01; a10 = n10; a11 = n11;
        }
        P2[p][0] = a00 * a00; P2[p][1] = a01 * a01;
        P2[p][2] = a10 * a10; P2[p][3] = a11 * a11;

        const v2f t2c = {cA2 * cA2, cB2 * cB2}, t2s = {sA2 * sA2, sB2 * sB2};
        const v2f t3c = {cA3 * cA3, cB3 * cB3}, t3s = {sA3 * sA3, sB3 * sB3};
        t23[p][0] = t2c * t3c; t23[p][1] = t2c * t3s;
        t23[p][2] = t2s * t3c; t23[p][3] = t2s * t3s;

        const v2f sa = s0 * s0, sb = t3s;
        const v2f na = 1.0f - sa, nb = 1.0f - sb;
        se[p][0] = na * nb; se[p][1] = na * sb;
        se[p][2] = sa * nb; se[p][3] = sa * sb;
    }

    __shared__ float red[4][NCLS][G];   // [wave][class][image]
    __shared__ float lg[G][NCLS];
    const int wave = tid >> 6;
    const int lane = tid & 63;
    const bool b5 = (lane & 32) != 0;
    const bool b4 = (lane & 16) != 0;
    const bool b3 = (lane & 8)  != 0;
    // image slot this lane's group owns after the reduce-scatter:
    const int gslot = ((lane >> 4) & 3) * 2 + ((lane >> 3) & 1);

    // prefetch class 0 weights
    float4 w0 = *reinterpret_cast<const float4*>(fc_w + 16 * t);
    float4 w1 = *reinterpret_cast<const float4*>(fc_w + 16 * t + 4);
    float4 w2 = *reinterpret_cast<const float4*>(fc_w + 16 * t + 8);
    float4 w3 = *reinterpret_cast<const float4*>(fc_w + 16 * t + 12);
    float4 ws = *reinterpret_cast<const float4*>(fc_w + 3136 + 4 * t);

    for (int c = 0; c < NCLS; ++c) {
        const float4 cw0 = w0, cw1 = w1, cw2 = w2, cw3 = w3, cws = ws;
        // prefetch next class (clamped redundant load on the last iteration)
        const int cn = (c + 1 < NCLS) ? c + 1 : c;
        const float* wrn = fc_w + (size_t)cn * FEATN;
        w0 = *reinterpret_cast<const float4*>(wrn + 16 * t);
        w1 = *reinterpret_cast<const float4*>(wrn + 16 * t + 4);
        w2 = *reinterpret_cast<const float4*>(wrn + 16 * t + 8);
        w3 = *reinterpret_cast<const float4*>(wrn + 16 * t + 12);
        ws = *reinterpret_cast<const float4*>(wrn + 3136 + 4 * t);

        v2f sv[NPAIR];
        #pragma unroll
        for (int p = 0; p < NPAIR; ++p) {
            v2f u0 = t23[p][0] * cw0.x + t23[p][1] * cw0.y + t23[p][2] * cw0.z + t23[p][3] * cw0.w;
            v2f u1 = t23[p][0] * cw1.x + t23[p][1] * cw1.y + t23[p][2] * cw1.z + t23[p][3] * cw1.w;
            v2f u2 = t23[p][0] * cw2.x + t23[p][1] * cw2.y + t23[p][2] * cw2.z + t23[p][3] * cw2.w;
            v2f u3 = t23[p][0] * cw3.x + t23[p][1] * cw3.y + t23[p][2] * cw3.z + t23[p][3] * cw3.w;
            v2f s  = P2[p][0] * u0 + P2[p][1] * u1 + P2[p][2] * u2 + P2[p][3] * u3;
            s += se[p][0] * cws.x + se[p][1] * cws.y + se[p][2] * cws.z + se[p][3] * cws.w;
            sv[p] = active ? s : (v2f){0.f, 0.f};
        }

        // ---- reduce-scatter butterfly: 8 values, 10 swizzles total ----
        // Stage 1 (xor 32): keep 2 pairs, send 2
        v2f k0 = b5 ? sv[2] : sv[0];
        v2f k1 = b5 ? sv[3] : sv[1];
        v2f o0 = b5 ? sv[0] : sv[2];
        v2f o1 = b5 ? sv[1] : sv[3];
        k0.x += __shfl_xor(o0.x, 32); k0.y += __shfl_xor(o0.y, 32);
        k1.x += __shfl_xor(o1.x, 32); k1.y += __shfl_xor(o1.y, 32);
        // Stage 2 (xor 16): keep 1 pair
        v2f kk = b4 ? k1 : k0;
        v2f oo = b4 ? k0 : k1;
        kk.x += __shfl_xor(oo.x, 16); kk.y += __shfl_xor(oo.y, 16);
        // Stage 3 (xor 8): split the two images of the pair
        float kv = b3 ? kk.y : kk.x;
        float ov = b3 ? kk.x : kk.y;
        kv += __shfl_xor(ov, 8);
        // Stages 4-6: flat butterfly within the 8-lane group
        kv += __shfl_xor(kv, 4);
        kv += __shfl_xor(kv, 2);
        kv += __shfl_xor(kv, 1);

        if ((lane & 7) == 0) red[wave][c][gslot] = kv;
    }

    __syncthreads();
    if (tid < G * NCLS) {
        const int g = tid / NCLS, c = tid - g * NCLS;
        lg[g][c] = red[0][c][g] + red[1][c][g] + red[2][c][g] + red[3][c][g] + fc_b[c];
    }
    __syncthreads();
    if (tid < G * NCLS) {
        const int g = tid / NCLS, c = tid - g * NCLS;
        float m = -1e30f;
        #pragma unroll
        for (int k = 0; k < NCLS; ++k) m = fmaxf(m, lg[g][k]);
        float ss = 0.f;
        #pragma unroll
        for (int k = 0; k < NCLS; ++k) ss += __expf(lg[g][k] - m);
        out[(size_t)(img0 + g) * NCLS + c] = lg[g][c] - m - __logf(ss);
    }
}

extern "C" void kernel_launch(void* const* d_in, const int* in_sizes, int n_in,
                              void* d_out, int out_size, void* d_ws, size_t ws_size,
                              hipStream_t stream) {
    const float* x    = (const float*)d_in[0];
    const float* fc_w = (const float*)d_in[1];
    const float* fc_b = (const float*)d_in[2];
    float* out = (float*)d_out;
    const int B = in_sizes[0] / 784;          // 8192
    const int grid = (B + G - 1) / G;         // 1024
    quanv_fused<<<grid, 256, 0, stream>>>(x, fc_w, fc_b, out);
}

// Round 4
// 88.344 us; speedup vs baseline: 1.2078x; 1.2078x over previous
//
#include <hip/hip_runtime.h>
#include <hip/hip_bf16.h>

typedef float v2f __attribute__((ext_vector_type(2)));
typedef short short8 __attribute__((ext_vector_type(8)));
typedef float f32x4 __attribute__((ext_vector_type(4)));

#define NCLS  10
#define FEATN 3920
#define GIMG  16          // images per block (MFMA M)
#define RSTR  996         // LDS row stride in dwords (== 4 mod 32 -> conflict-free A reads)
// K padded to 3936 = 123 kb-blocks of 32. Tile0: kb 0..61 (k 0..1983 = filter patches 0..123)
// Tile1: kb 62..122 (k 1984..3935 = filter patches 124..195, sampler all, 16 zero-pad)

__device__ __forceinline__ unsigned packbf(float a, float b) {
    __hip_bfloat162 h = __float22bfloat162_rn(float2{a, b});
    unsigned u; __builtin_memcpy(&u, &h, 4); return u;
}

// ---- pre-pass: W fp32 -> bf16 in MFMA B-fragment order ----
// ws[kb*512 + lane*8 + j] = W[n = lane&15][k = kb*32 + (lane>>4)*8 + j]  (0 if n>=10 or k>=3920)
__global__ void conv_w(const float* __restrict__ fc_w, __hip_bfloat16* __restrict__ ws) {
    const int id = blockIdx.x * 256 + threadIdx.x;      // 0..62975
    const int kb = id >> 9;
    const int r  = id & 511;
    const int l  = r >> 3;
    const int j  = r & 7;
    const int n  = l & 15;
    const int k  = kb * 32 + ((l >> 4) << 3) + j;
    const float w = (n < NCLS && k < FEATN) ? fc_w[n * FEATN + k] : 0.f;
    ws[id] = __float2bfloat16(w);
}

// ---- filter feature task: patch p, image pair q (images 2q, 2q+1), write 16 bf16 each ----
__device__ __forceinline__ void do_filter(const float* __restrict__ base, int p, int q,
                                          int dw, unsigned* __restrict__ lds) {
    const int pi = p / 14, pj = p - pi * 14;
    const int offT = pi * 56 + pj * 2;
    const float* iA = base + (size_t)(2 * q) * 784;
    const float* iB = iA + 784;
    const float2 tA = *reinterpret_cast<const float2*>(iA + offT);
    const float2 bA = *reinterpret_cast<const float2*>(iA + offT + 28);
    const float2 tB = *reinterpret_cast<const float2*>(iB + offT);
    const float2 bB = *reinterpret_cast<const float2*>(iB + offT + 28);

    float sA0,cA0,sA1,cA1,sA2,cA2,sA3,cA3;
    float sB0,cB0,sB1,cB1,sB2,cB2,sB3,cB3;
    __sincosf(0.5f * tA.x, &sA0, &cA0); __sincosf(0.5f * tA.y, &sA1, &cA1);
    __sincosf(0.5f * bA.x, &sA2, &cA2); __sincosf(0.5f * bA.y, &sA3, &cA3);
    __sincosf(0.5f * tB.x, &sB0, &cB0); __sincosf(0.5f * tB.y, &sB1, &cB1);
    __sincosf(0.5f * bB.x, &sB2, &cB2); __sincosf(0.5f * bB.y, &sB3, &cB3);

    const v2f c0 = {cA0, cB0}, s0 = {sA0, sB0};
    const v2f c1 = {cA1, cB1}, s1 = {sA1, sB1};
    v2f a00 = c0 * c1, a01 = c0 * s1, a10 = s0 * c1, a11 = s0 * s1;
    #pragma unroll
    for (int r = 0; r < 8; ++r) {
        const v2f b10 = a11, b11 = a10;          // CX(0,1)
        const v2f n00 = c0 * a00 - s0 * b10;     // RY(p0)
        const v2f n01 = c0 * a01 - s0 * b11;
        const v2f n10 = s0 * a00 + c0 * b10;
        const v2f n11 = s0 * a01 + c0 * b11;
        a00 = n00; a01 = n01; a10 = n10; a11 = n11;
    }
    v2f P2[4];
    P2[0] = a00 * a00; P2[1] = a01 * a01; P2[2] = a10 * a10; P2[3] = a11 * a11;
    const v2f t2c = {cA2*cA2, cB2*cB2}, t2s = {sA2*sA2, sB2*sB2};
    const v2f t3c = {cA3*cA3, cB3*cB3}, t3s = {sA3*sA3, sB3*sB3};
    v2f T[4];
    T[0] = t2c * t3c; T[1] = t2c * t3s; T[2] = t2s * t3c; T[3] = t2s * t3s;

    unsigned dA[8], dB[8];
    #pragma unroll
    for (int m = 0; m < 4; ++m) {
        const v2f f0 = P2[m] * T[0], f1 = P2[m] * T[1];
        const v2f f2 = P2[m] * T[2], f3 = P2[m] * T[3];
        dA[2*m]   = packbf(f0.x, f1.x); dA[2*m+1] = packbf(f2.x, f3.x);
        dB[2*m]   = packbf(f0.y, f1.y); dB[2*m+1] = packbf(f2.y, f3.y);
    }
    unsigned* rowA = lds + (2 * q) * RSTR + dw;
    unsigned* rowB = rowA + RSTR;
    *reinterpret_cast<uint4*>(rowA)     = uint4{dA[0], dA[1], dA[2], dA[3]};
    *reinterpret_cast<uint4*>(rowA + 4) = uint4{dA[4], dA[5], dA[6], dA[7]};
    *reinterpret_cast<uint4*>(rowB)     = uint4{dB[0], dB[1], dB[2], dB[3]};
    *reinterpret_cast<uint4*>(rowB + 4) = uint4{dB[4], dB[5], dB[6], dB[7]};
}

// ---- sampler task: patch p, pair q -> 4 bf16 per image at tile1 dword 576 + 2p ----
__device__ __forceinline__ void do_sampler(const float* __restrict__ base, int p, int q,
                                           unsigned* __restrict__ lds) {
    const int pi = p / 14, pj = p - pi * 14;
    const int offT = pi * 56 + pj * 2;
    const float* iA = base + (size_t)(2 * q) * 784;
    const float* iB = iA + 784;
    const float p0A = iA[offT],  p3A = iA[offT + 29];
    const float p0B = iB[offT],  p3B = iB[offT + 29];
    const float sA = __sinf(0.5f * p0A), tA = __sinf(0.5f * p3A);
    const float sB = __sinf(0.5f * p0B), tB = __sinf(0.5f * p3B);
    const float saA = sA*sA, sbA = tA*tA, naA = 1.f - saA, nbA = 1.f - sbA;
    const float saB = sB*sB, sbB = tB*tB, naB = 1.f - saB, nbB = 1.f - sbB;
    const int dw = 576 + 2 * p;
    *reinterpret_cast<uint2*>(lds + (2*q)   * RSTR + dw) =
        uint2{packbf(naA*nbA, naA*sbA), packbf(saA*nbA, saA*sbA)};
    *reinterpret_cast<uint2*>(lds + (2*q+1) * RSTR + dw) =
        uint2{packbf(naB*nbB, naB*sbB), packbf(saB*nbB, saB*sbB)};
}

__global__ __launch_bounds__(256, 2)
void quanv_mfma(const float* __restrict__ x,
                const short* __restrict__ wsb,     // bf16 bits, B-fragment order
                const float* __restrict__ fc_b,
                float* __restrict__ out) {
    __shared__ __align__(16) unsigned lds[GIMG * RSTR];   // 63744 B
    const int tid  = threadIdx.x;
    const int img0 = blockIdx.x * GIMG;
    const float* base = x + (size_t)img0 * 784;
    const int lane = tid & 63;
    const int wave = tid >> 6;
    const int am   = lane & 15;
    const int ach  = lane >> 4;
    const unsigned aoff = am * RSTR + ach * 4;

    f32x4 acc = {0.f, 0.f, 0.f, 0.f};

    // ================= TILE 0: filter patches 0..123 (kb 0..61) =================
    #pragma unroll
    for (int i = 0; i < 4; ++i) {
        const int tau = tid + (i << 8);
        if (tau < 992) do_filter(base, tau >> 3, tau & 7, (tau >> 3) << 3, lds);
    }
    __syncthreads();
    for (int kb = wave; kb < 62; kb += 4) {
        const short8 a = *reinterpret_cast<const short8*>(lds + aoff + kb * 16);
        const short8 b = *reinterpret_cast<const short8*>(wsb + (size_t)kb * 512 + lane * 8);
        acc = __builtin_amdgcn_mfma_f32_16x16x32_bf16(a, b, acc, 0, 0, 0);
    }
    __syncthreads();

    // ================= TILE 1: filter 124..195, sampler, pad (kb 62..122) =======
    #pragma unroll
    for (int i = 0; i < 3; ++i) {
        const int tau = tid + (i << 8);
        if (tau < 576) {
            const int p = 124 + (tau >> 3);
            do_filter(base, p, tau & 7, (p - 124) << 3, lds);
        }
    }
    #pragma unroll
    for (int i = 0; i < 7; ++i) {
        const int ka = tid + (i << 8);
        if (ka < 1568) do_sampler(base, ka >> 3, ka & 7, lds);
    }
    if (tid < GIMG) {  // zero-pad k 3920..3935 -> tile1 dwords 968..975
        unsigned* z = lds + tid * RSTR + 968;
        *reinterpret_cast<uint4*>(z)     = uint4{0, 0, 0, 0};
        *reinterpret_cast<uint4*>(z + 4) = uint4{0, 0, 0, 0};
    }
    __syncthreads();
    for (int kb = wave; kb < 61; kb += 4) {
        const short8 a = *reinterpret_cast<const short8*>(lds + aoff + kb * 16);
        const short8 b = *reinterpret_cast<const short8*>(wsb + (size_t)(62 + kb) * 512 + lane * 8);
        acc = __builtin_amdgcn_mfma_f32_16x16x32_bf16(a, b, acc, 0, 0, 0);
    }
    __syncthreads();

    // ================= epilogue: combine 4 waves, bias, log-softmax =============
    float* f = reinterpret_cast<float*>(lds);
    f[wave * 256 +   0 + lane] = acc[0];
    f[wave * 256 +  64 + lane] = acc[1];
    f[wave * 256 + 128 + lane] = acc[2];
    f[wave * 256 + 192 + lane] = acc[3];
    __syncthreads();
    if (tid < GIMG * NCLS) {
        const int g = tid / NCLS, c = tid - g * NCLS;
        const int li = ((g >> 2) << 4) + c;     // lane holding D[g][c]
        const int ri = (g & 3) << 6;            // reg slot
        float v = f[ri + li] + f[256 + ri + li] + f[512 + ri + li] + f[768 + ri + li];
        f[1024 + tid] = v + fc_b[c];
    }
    __syncthreads();
    if (tid < GIMG * NCLS) {
        const int g = tid / NCLS, c = tid - g * NCLS;
        const float* lg = f + 1024 + g * NCLS;
        float m = -1e30f;
        #pragma unroll
        for (int k = 0; k < NCLS; ++k) m = fmaxf(m, lg[k]);
        float ss = 0.f;
        #pragma unroll
        for (int k = 0; k < NCLS; ++k) ss += __expf(lg[k] - m);
        out[(size_t)(img0 + g) * NCLS + c] = lg[c] - m - __logf(ss);
    }
}

extern "C" void kernel_launch(void* const* d_in, const int* in_sizes, int n_in,
                              void* d_out, int out_size, void* d_ws, size_t ws_size,
                              hipStream_t stream) {
    const float* x    = (const float*)d_in[0];
    const float* fc_w = (const float*)d_in[1];
    const float* fc_b = (const float*)d_in[2];
    float* out = (float*)d_out;

    // pre-pass: 123 kb-blocks * 512 = 62976 bf16 elements
    conv_w<<<246, 256, 0, stream>>>(fc_w, (__hip_bfloat16*)d_ws);

    const int B = in_sizes[0] / 784;            // 8192
    const int grid = B / GIMG;                  // 512
    quanv_mfma<<<grid, 256, 0, stream>>>(x, (const short*)d_ws, fc_b, out);
}

// Round 5
// 85.321 us; speedup vs baseline: 1.2505x; 1.0354x over previous
//
#include <hip/hip_runtime.h>
#include <hip/hip_bf16.h>

typedef float v2f __attribute__((ext_vector_type(2)));
typedef short short8 __attribute__((ext_vector_type(8)));
typedef float f32x4 __attribute__((ext_vector_type(4)));

#define NCLS  10
#define FEATN 3920
#define GIMG  8            // images per block; grid = 1024 -> 4 blocks/CU
#define RSTR  532          // LDS row stride in dwords (mult of 4; %32==20)
// K permuted + padded to 3936 = 123 kb (kb = 32 k).
// Tile t in {0,1,2}: patches [48t,48t+48): filter block 768k (24kb) then sampler 192k (6kb).
// Tile 3: patches [144,196): filter 832k (26kb), sampler 208k, pad 16k (33kb total).

__device__ __forceinline__ unsigned packbf(float a, float b) {
    __hip_bfloat162 h = __float22bfloat162_rn(float2{a, b});
    unsigned u; __builtin_memcpy(&u, &h, 4); return u;
}

// ---- pre-pass: W fp32 -> bf16, MFMA B-fragment order, permuted K ----
// ws[kb*512 + lane*8 + j] = W[n = lane&15][kk = kb*32 + (lane>>4)*8 + j] in NEW k order
__global__ void conv_w(const float* __restrict__ fc_w, __hip_bfloat16* __restrict__ ws) {
    const int id = blockIdx.x * 256 + threadIdx.x;          // 0..62975
    if (id >= 123 * 512) return;
    const int kb = id >> 9, r = id & 511, l = r >> 3, j0 = r & 7;
    const int n  = l & 15;
    const int kk = kb * 32 + ((l >> 4) << 3) + j0;          // new-layout k
    float w = 0.f;
    if (n < NCLS) {
        const int t    = (kk < 2880) ? kk / 960 : 3;
        const int base = 960 * t;
        const int P0   = 48 * t;
        const int np   = (t == 3) ? 52 : 48;
        const int u    = kk - base;
        int korig = -1;
        if (u < np * 16) {
            korig = 16 * (P0 + (u >> 4)) + (u & 15);        // filter feature
        } else {
            const int v = u - np * 16;
            if (v < np * 4) korig = 3136 + 4 * (P0 + (v >> 2)) + (v & 3);  // sampler
        }
        if (korig >= 0) w = fc_w[n * FEATN + korig];
    }
    ws[id] = __float2bfloat16(w);
}

__global__ __launch_bounds__(256, 4)
void quanv_mfma(const float* __restrict__ x,
                const short* __restrict__ wsb,     // bf16 bits, B-fragment order
                const float* __restrict__ fc_b,
                float* __restrict__ out) {
    __shared__ __align__(16) unsigned lds[GIMG * RSTR];     // 17024 B
    const int tid  = threadIdx.x;
    const int lane = tid & 63;
    const int wave = tid >> 6;
    const int img0 = blockIdx.x * GIMG;
    const float* base = x + (size_t)img0 * 784;
    const int am  = lane & 15;
    const int ach = lane >> 4;
    const unsigned aoff = (unsigned)((am & 7) * RSTR + ach * 4);  // dup rows 8..15

    // ---- preload all 4 tiles' pixels; one fused task per thread per tile ----
    float2 pix[4][4];
    int lpv[4], qv[4];
    bool act[4];
    #pragma unroll
    for (int t = 0; t < 4; ++t) {
        const int np = (t == 3) ? 52 : 48;
        const int P0 = 48 * t;
        const bool a = tid < np * 4;
        const int tt = a ? tid : 0;
        const int q  = tt / np;
        const int lp = tt - q * np;
        const int p  = P0 + lp;
        const int pi = p / 14, pj = p - pi * 14;
        const int off = pi * 56 + pj * 2;
        const float* iA = base + (size_t)(2 * q) * 784;
        pix[t][0] = *reinterpret_cast<const float2*>(iA + off);
        pix[t][1] = *reinterpret_cast<const float2*>(iA + off + 28);
        pix[t][2] = *reinterpret_cast<const float2*>(iA + 784 + off);
        pix[t][3] = *reinterpret_cast<const float2*>(iA + 784 + off + 28);
        lpv[t] = lp; qv[t] = q; act[t] = a;
    }

    f32x4 acc = {0.f, 0.f, 0.f, 0.f};

    #pragma unroll
    for (int t = 0; t < 4; ++t) {
        const int np  = (t == 3) ? 52 : 48;
        const int nkb = (t == 3) ? 33 : 30;
        const int kbb = 30 * t;

        if (act[t]) {
            const float2 tA = pix[t][0], bA = pix[t][1];
            const float2 tB = pix[t][2], bB = pix[t][3];
            float sA0,cA0,sA1,cA1,sA2,cA2,sA3,cA3;
            float sB0,cB0,sB1,cB1,sB2,cB2,sB3,cB3;
            __sincosf(0.5f * tA.x, &sA0, &cA0); __sincosf(0.5f * tA.y, &sA1, &cA1);
            __sincosf(0.5f * bA.x, &sA2, &cA2); __sincosf(0.5f * bA.y, &sA3, &cA3);
            __sincosf(0.5f * tB.x, &sB0, &cB0); __sincosf(0.5f * tB.y, &sB1, &cB1);
            __sincosf(0.5f * bB.x, &sB2, &cB2); __sincosf(0.5f * bB.y, &sB3, &cB3);

            const v2f c0 = {cA0, cB0}, s0 = {sA0, sB0};
            const v2f c1 = {cA1, cB1}, s1 = {sA1, sB1};
            v2f a00 = c0 * c1, a01 = c0 * s1, a10 = s0 * c1, a11 = s0 * s1;
            #pragma unroll
            for (int r = 0; r < 8; ++r) {
                const v2f b10 = a11, b11 = a10;          // CX(0,1)
                const v2f n00 = c0 * a00 - s0 * b10;     // RY(p0)
                const v2f n01 = c0 * a01 - s0 * b11;
                const v2f n10 = s0 * a00 + c0 * b10;
                const v2f n11 = s0 * a01 + c0 * b11;
                a00 = n00; a01 = n01; a10 = n10; a11 = n11;
            }
            v2f P2[4];
            P2[0] = a00 * a00; P2[1] = a01 * a01; P2[2] = a10 * a10; P2[3] = a11 * a11;
            const v2f t2c = {cA2*cA2, cB2*cB2}, t2s = {sA2*sA2, sB2*sB2};
            const v2f t3c = {cA3*cA3, cB3*cB3}, t3s = {sA3*sA3, sB3*sB3};
            v2f T[4];
            T[0] = t2c * t3c; T[1] = t2c * t3s; T[2] = t2s * t3c; T[3] = t2s * t3s;

            unsigned dA[8], dB[8];
            #pragma unroll
            for (int m = 0; m < 4; ++m) {
                const v2f f0 = P2[m] * T[0], f1 = P2[m] * T[1];
                const v2f f2 = P2[m] * T[2], f3 = P2[m] * T[3];
                dA[2*m]   = packbf(f0.x, f1.x); dA[2*m+1] = packbf(f2.x, f3.x);
                dB[2*m]   = packbf(f0.y, f1.y); dB[2*m+1] = packbf(f2.y, f3.y);
            }
            // fused sampler (p0 = tA.x -> s0; p3 = bA.y -> t3s)
            const v2f sa = s0 * s0, sb = t3s;
            const v2f na = 1.0f - sa, nb = 1.0f - sb;
            const v2f e0 = na * nb, e1 = na * sb, e2 = sa * nb, e3 = sa * sb;

            const int lp = lpv[t], q = qv[t];
            unsigned* rowA = lds + (2 * q) * RSTR;
            unsigned* rowB = rowA + RSTR;
            *reinterpret_cast<uint4*>(rowA + lp * 8)     = uint4{dA[0], dA[1], dA[2], dA[3]};
            *reinterpret_cast<uint4*>(rowA + lp * 8 + 4) = uint4{dA[4], dA[5], dA[6], dA[7]};
            *reinterpret_cast<uint2*>(rowA + np * 8 + lp * 2) =
                uint2{packbf(e0.x, e1.x), packbf(e2.x, e3.x)};
            *reinterpret_cast<uint4*>(rowB + lp * 8)     = uint4{dB[0], dB[1], dB[2], dB[3]};
            *reinterpret_cast<uint4*>(rowB + lp * 8 + 4) = uint4{dB[4], dB[5], dB[6], dB[7]};
            *reinterpret_cast<uint2*>(rowB + np * 8 + lp * 2) =
                uint2{packbf(e0.y, e1.y), packbf(e2.y, e3.y)};
        }
        if (t == 3 && tid < 64)    // zero-pad k 3920..3935: rows 0..7, dwords 520..527
            lds[(tid >> 3) * RSTR + 520 + (tid & 7)] = 0u;
        __syncthreads();

        for (int kb = wave; kb < nkb; kb += 4) {
            const short8 a = *reinterpret_cast<const short8*>(lds + aoff + kb * 16);
            const short8 b = *reinterpret_cast<const short8*>(wsb + (size_t)(kbb + kb) * 512 + lane * 8);
            acc = __builtin_amdgcn_mfma_f32_16x16x32_bf16(a, b, acc, 0, 0, 0);
        }
        __syncthreads();
    }

    // ---- epilogue: combine 4 waves' K-split accs, bias, log-softmax ----
    float* f = reinterpret_cast<float*>(lds);
    f[wave * 256 +   0 + lane] = acc[0];
    f[wave * 256 +  64 + lane] = acc[1];
    f[wave * 256 + 128 + lane] = acc[2];
    f[wave * 256 + 192 + lane] = acc[3];
    __syncthreads();
    if (tid < GIMG * NCLS) {
        const int g = tid / NCLS, c = tid - g * NCLS;
        const int li = ((g >> 2) << 4) + c;   // D: col=lane&15, row=(lane>>4)*4+reg
        const int ri = (g & 3) << 6;
        float v = f[ri + li] + f[256 + ri + li] + f[512 + ri + li] + f[768 + ri + li];
        f[1024 + tid] = v + fc_b[c];
    }
    __syncthreads();
    if (tid < GIMG * NCLS) {
        const int g = tid / NCLS, c = tid - g * NCLS;
        const float* lg = f + 1024 + g * NCLS;
        float m = -1e30f;
        #pragma unroll
        for (int k = 0; k < NCLS; ++k) m = fmaxf(m, lg[k]);
        float ss = 0.f;
        #pragma unroll
        for (int k = 0; k < NCLS; ++k) ss += __expf(lg[k] - m);
        out[(size_t)(img0 + g) * NCLS + c] = lg[c] - m - __logf(ss);
    }
}

extern "C" void kernel_launch(void* const* d_in, const int* in_sizes, int n_in,
                              void* d_out, int out_size, void* d_ws, size_t ws_size,
                              hipStream_t stream) {
    const float* x    = (const float*)d_in[0];
    const float* fc_w = (const float*)d_in[1];
    const float* fc_b = (const float*)d_in[2];
    float* out = (float*)d_out;

    conv_w<<<246, 256, 0, stream>>>(fc_w, (__hip_bfloat16*)d_ws);

    const int B = in_sizes[0] / 784;            // 8192
    const int grid = B / GIMG;                  // 1024
    quanv_mfma<<<grid, 256, 0, stream>>>(x, (const short*)d_ws, fc_b, out);
}

// Round 6
// 84.838 us; speedup vs baseline: 1.2577x; 1.0057x over previous
//
#include <hip/hip_runtime.h>
#include <hip/hip_bf16.h>

typedef float v2f __attribute__((ext_vector_type(2)));
typedef short short8 __attribute__((ext_vector_type(8)));
typedef float f32x4 __attribute__((ext_vector_type(4)));

#define NCLS  10
#define FEATN 3920
#define GIMG  8            // images per block; grid = 1024 -> 4 blocks/CU
#define RSTR  532          // LDS row stride in dwords (mult of 4; %32==20)
// K permuted + padded to 3936 = 123 kb (kb = 32 k).
// Tile t in {0,1,2}: patches [48t,48t+48): filter block 768k (24kb) then sampler 192k (6kb).
// Tile 3: patches [144,196): filter 832k (26kb), sampler 208k, pad 16k (33kb total).

__device__ __forceinline__ unsigned packbf(float a, float b) {
    __hip_bfloat162 h = __float22bfloat162_rn(float2{a, b});
    unsigned u; __builtin_memcpy(&u, &h, 4); return u;
}

// sin/cos of (0.5*v) via native v_sin_f32/v_cos_f32 (input in revolutions).
// v in [0,1) -> r in [0,0.08] revolutions: no range reduction needed.
__device__ __forceinline__ void fastsc(float v, float& s, float& c) {
    const float r = v * 0.07957747154594767f;   // 0.5 / (2*pi)
#if __has_builtin(__builtin_amdgcn_sinf)
    s = __builtin_amdgcn_sinf(r);
    c = __builtin_amdgcn_cosf(r);
#else
    s = __sinf(0.5f * v);
    c = __cosf(0.5f * v);
#endif
}

// ---- pre-pass: W fp32 -> bf16, MFMA B-fragment order, permuted K ----
// ws[kb*512 + lane*8 + j] = W[n = lane&15][kk = kb*32 + (lane>>4)*8 + j] in NEW k order
__global__ void conv_w(const float* __restrict__ fc_w, __hip_bfloat16* __restrict__ ws) {
    const int id = blockIdx.x * 256 + threadIdx.x;          // 0..62975
    if (id >= 123 * 512) return;
    const int kb = id >> 9, r = id & 511, l = r >> 3, j0 = r & 7;
    const int n  = l & 15;
    const int kk = kb * 32 + ((l >> 4) << 3) + j0;          // new-layout k
    float w = 0.f;
    if (n < NCLS) {
        const int t    = (kk < 2880) ? kk / 960 : 3;
        const int base = 960 * t;
        const int P0   = 48 * t;
        const int np   = (t == 3) ? 52 : 48;
        const int u    = kk - base;
        int korig = -1;
        if (u < np * 16) {
            korig = 16 * (P0 + (u >> 4)) + (u & 15);        // filter feature
        } else {
            const int v = u - np * 16;
            if (v < np * 4) korig = 3136 + 4 * (P0 + (v >> 2)) + (v & 3);  // sampler
        }
        if (korig >= 0) w = fc_w[n * FEATN + korig];
    }
    ws[id] = __float2bfloat16(w);
}

__global__ __launch_bounds__(256, 4)
void quanv_mfma(const float* __restrict__ x,
                const short* __restrict__ wsb,     // bf16 bits, B-fragment order
                const float* __restrict__ fc_b,
                float* __restrict__ out) {
    __shared__ __align__(16) unsigned lds[GIMG * RSTR];     // 17024 B
    const int tid  = threadIdx.x;
    const int lane = tid & 63;
    const int wave = tid >> 6;
    const int img0 = blockIdx.x * GIMG;
    const float* base = x + (size_t)img0 * 784;
    const int am  = lane & 15;
    const int ach = lane >> 4;
    const unsigned aoff = (unsigned)((am & 7) * RSTR + ach * 4);  // dup rows 8..15

    // ---- preload all 4 tiles' pixels; one fused task per thread per tile ----
    float2 pix[4][4];
    int lpv[4], qv[4];
    bool act[4];
    #pragma unroll
    for (int t = 0; t < 4; ++t) {
        const int np = (t == 3) ? 52 : 48;
        const int P0 = 48 * t;
        const bool a = tid < np * 4;
        const int tt = a ? tid : 0;
        const int q  = tt / np;
        const int lp = tt - q * np;
        const int p  = P0 + lp;
        const int pi = p / 14, pj = p - pi * 14;
        const int off = pi * 56 + pj * 2;
        const float* iA = base + (size_t)(2 * q) * 784;
        pix[t][0] = *reinterpret_cast<const float2*>(iA + off);
        pix[t][1] = *reinterpret_cast<const float2*>(iA + off + 28);
        pix[t][2] = *reinterpret_cast<const float2*>(iA + 784 + off);
        pix[t][3] = *reinterpret_cast<const float2*>(iA + 784 + off + 28);
        lpv[t] = lp; qv[t] = q; act[t] = a;
    }

    f32x4 acc = {0.f, 0.f, 0.f, 0.f};

    #pragma unroll
    for (int t = 0; t < 4; ++t) {
        const int np  = (t == 3) ? 52 : 48;
        const int nkb = (t == 3) ? 33 : 30;
        const int kbb = 30 * t;

        if (act[t]) {
            const float2 tA = pix[t][0], bA = pix[t][1];
            const float2 tB = pix[t][2], bB = pix[t][3];
            float sA0,cA0,sA1,cA1,sA2,cA2,sA3,cA3;
            float sB0,cB0,sB1,cB1,sB2,cB2,sB3,cB3;
            fastsc(tA.x, sA0, cA0); fastsc(tA.y, sA1, cA1);
            fastsc(bA.x, sA2, cA2); fastsc(bA.y, sA3, cA3);
            fastsc(tB.x, sB0, cB0); fastsc(tB.y, sB1, cB1);
            fastsc(bB.x, sB2, cB2); fastsc(bB.y, sB3, cB3);

            const v2f c0 = {cA0, cB0}, s0 = {sA0, sB0};
            const v2f c1 = {cA1, cB1}, s1 = {sA1, sB1};
            v2f a00 = c0 * c1, a01 = c0 * s1, a10 = s0 * c1, a11 = s0 * s1;
            #pragma unroll
            for (int r = 0; r < 8; ++r) {
                const v2f b10 = a11, b11 = a10;          // CX(0,1)
                const v2f n00 = c0 * a00 - s0 * b10;     // RY(p0)
                const v2f n01 = c0 * a01 - s0 * b11;
                const v2f n10 = s0 * a00 + c0 * b10;
                const v2f n11 = s0 * a01 + c0 * b11;
                a00 = n00; a01 = n01; a10 = n10; a11 = n11;
            }
            v2f P2[4];
            P2[0] = a00 * a00; P2[1] = a01 * a01; P2[2] = a10 * a10; P2[3] = a11 * a11;
            const v2f t2c = {cA2*cA2, cB2*cB2}, t2s = {sA2*sA2, sB2*sB2};
            const v2f t3c = {cA3*cA3, cB3*cB3}, t3s = {sA3*sA3, sB3*sB3};
            v2f T[4];
            T[0] = t2c * t3c; T[1] = t2c * t3s; T[2] = t2s * t3c; T[3] = t2s * t3s;

            unsigned dA[8], dB[8];
            #pragma unroll
            for (int m = 0; m < 4; ++m) {
                const v2f f0 = P2[m] * T[0], f1 = P2[m] * T[1];
                const v2f f2 = P2[m] * T[2], f3 = P2[m] * T[3];
                dA[2*m]   = packbf(f0.x, f1.x); dA[2*m+1] = packbf(f2.x, f3.x);
                dB[2*m]   = packbf(f0.y, f1.y); dB[2*m+1] = packbf(f2.y, f3.y);
            }
            // fused sampler (p0 -> s0; p3 -> t3s)
            const v2f sa = s0 * s0, sb = t3s;
            const v2f na = 1.0f - sa, nb = 1.0f - sb;
            const v2f e0 = na * nb, e1 = na * sb, e2 = sa * nb, e3 = sa * sb;

            const int lp = lpv[t], q = qv[t];
            unsigned* rowA = lds + (2 * q) * RSTR;
            unsigned* rowB = rowA + RSTR;
            *reinterpret_cast<uint4*>(rowA + lp * 8)     = uint4{dA[0], dA[1], dA[2], dA[3]};
            *reinterpret_cast<uint4*>(rowA + lp * 8 + 4) = uint4{dA[4], dA[5], dA[6], dA[7]};
            *reinterpret_cast<uint2*>(rowA + np * 8 + lp * 2) =
                uint2{packbf(e0.x, e1.x), packbf(e2.x, e3.x)};
            *reinterpret_cast<uint4*>(rowB + lp * 8)     = uint4{dB[0], dB[1], dB[2], dB[3]};
            *reinterpret_cast<uint4*>(rowB + lp * 8 + 4) = uint4{dB[4], dB[5], dB[6], dB[7]};
            *reinterpret_cast<uint2*>(rowB + np * 8 + lp * 2) =
                uint2{packbf(e0.y, e1.y), packbf(e2.y, e3.y)};
        }
        if (t == 3 && tid < 64)    // zero-pad k 3920..3935: rows 0..7, dwords 520..527
            lds[(tid >> 3) * RSTR + 520 + (tid & 7)] = 0u;
        __syncthreads();

        for (int kb = wave; kb < nkb; kb += 4) {
            const short8 a = *reinterpret_cast<const short8*>(lds + aoff + kb * 16);
            const short8 b = *reinterpret_cast<const short8*>(wsb + (size_t)(kbb + kb) * 512 + lane * 8);
            acc = __builtin_amdgcn_mfma_f32_16x16x32_bf16(a, b, acc, 0, 0, 0);
        }
        __syncthreads();
    }

    // ---- epilogue: combine 4 waves' K-split accs, bias, log-softmax ----
    float* f = reinterpret_cast<float*>(lds);
    f[wave * 256 +   0 + lane] = acc[0];
    f[wave * 256 +  64 + lane] = acc[1];
    f[wave * 256 + 128 + lane] = acc[2];
    f[wave * 256 + 192 + lane] = acc[3];
    __syncthreads();
    if (tid < GIMG * NCLS) {
        const int g = tid / NCLS, c = tid - g * NCLS;
        const int li = ((g >> 2) << 4) + c;   // D: col=lane&15, row=(lane>>4)*4+reg
        const int ri = (g & 3) << 6;
        float v = f[ri + li] + f[256 + ri + li] + f[512 + ri + li] + f[768 + ri + li];
        f[1024 + tid] = v + fc_b[c];
    }
    __syncthreads();
    if (tid < GIMG * NCLS) {
        const int g = tid / NCLS, c = tid - g * NCLS;
        const float* lg = f + 1024 + g * NCLS;
        float m = -1e30f;
        #pragma unroll
        for (int k = 0; k < NCLS; ++k) m = fmaxf(m, lg[k]);
        float ss = 0.f;
        #pragma unroll
        for (int k = 0; k < NCLS; ++k) ss += __expf(lg[k] - m);
        out[(size_t)(img0 + g) * NCLS + c] = lg[c] - m - __logf(ss);
    }
}

extern "C" void kernel_launch(void* const* d_in, const int* in_sizes, int n_in,
                              void* d_out, int out_size, void* d_ws, size_t ws_size,
                              hipStream_t stream) {
    const float* x    = (const float*)d_in[0];
    const float* fc_w = (const float*)d_in[1];
    const float* fc_b = (const float*)d_in[2];
    float* out = (float*)d_out;

    conv_w<<<246, 256, 0, stream>>>(fc_w, (__hip_bfloat16*)d_ws);

    const int B = in_sizes[0] / 784;            // 8192
    const int grid = B / GIMG;                  // 1024
    quanv_mfma<<<grid, 256, 0, stream>>>(x, (const short*)d_ws, fc_b, out);
}